// Round 3
// baseline (3261.207 us; speedup 1.0000x reference)
//
#include <hip/hip_runtime.h>

// Problem constants (from reference)
constexpr int N0 = 50000, N1 = 150000, N2 = 20000, N3 = 5000, N4 = 1000;
constexpr int E0 = 800000, E1 = 1500000, NNZ01 = 300000;
constexpr int D = 64;

// Coarse destination buckets: 128 rows each, LDS-accumulated.
constexpr int BROWS = 128;
constexpr int NBKT00 = (N0 + BROWS - 1) / BROWS;   // 391
constexpr int NBKT11 = (N1 + BROWS - 1) / BROWS;   // 1172
constexpr int BKT_BASE00 = 0;
constexpr int BKT_BASE11 = NBKT00;                 // 391
constexpr int BKT_BASE10 = NBKT00 + NBKT11;        // 1563
constexpr int BKT_BASE01 = 2 * NBKT00 + NBKT11;    // 1954
constexpr int NBKT_TOT = 2 * NBKT00 + 2 * NBKT11;  // 3126
constexpr int NREC = E0 + E1 + 2 * NNZ01;          // 2.9M

// ---------------------------------------------------------------------------
// Dual GEMM: ya = x@Wa, yb = x@Wb (reads x once). 64-row tile, 256 threads,
// each thread 4 rows x 4 cols for both outputs. f32 vector ALU (no fp32 MFMA).
// ---------------------------------------------------------------------------
__global__ __launch_bounds__(256) void gemm64_dual(const float* __restrict__ x,
                                                   const float* __restrict__ Wa,
                                                   const float* __restrict__ Wb,
                                                   float* __restrict__ ya,
                                                   float* __restrict__ yb, int n) {
    __shared__ float Ws[2][64][64];
    __shared__ float Xs[64][64];
    const int t = threadIdx.x;
    for (int i = t; i < 64 * 64; i += 256) {
        Ws[0][i >> 6][i & 63] = Wa[i];
        Ws[1][i >> 6][i & 63] = Wb[i];
    }
    const long row0 = (long)blockIdx.x * 64;
    const int nrow = min(64, n - (int)row0);
    {
        const float4* xv = (const float4*)(x + row0 * D);
        float4* xs = (float4*)&Xs[0][0];
        for (int i = t; i < nrow * 16; i += 256) xs[i] = xv[i];
    }
    __syncthreads();
    const int r0 = (t >> 4) * 4;
    const int c  = (t & 15) * 4;
    float acca[4][4] = {};
    float accb[4][4] = {};
#pragma unroll
    for (int k = 0; k < 64; ++k) {
        const float4 wa = *(const float4*)&Ws[0][k][c];
        const float4 wb = *(const float4*)&Ws[1][k][c];
#pragma unroll
        for (int rr = 0; rr < 4; ++rr) {
            const float xv = Xs[r0 + rr][k];
            acca[rr][0] = fmaf(xv, wa.x, acca[rr][0]);
            acca[rr][1] = fmaf(xv, wa.y, acca[rr][1]);
            acca[rr][2] = fmaf(xv, wa.z, acca[rr][2]);
            acca[rr][3] = fmaf(xv, wa.w, acca[rr][3]);
            accb[rr][0] = fmaf(xv, wb.x, accb[rr][0]);
            accb[rr][1] = fmaf(xv, wb.y, accb[rr][1]);
            accb[rr][2] = fmaf(xv, wb.z, accb[rr][2]);
            accb[rr][3] = fmaf(xv, wb.w, accb[rr][3]);
        }
    }
#pragma unroll
    for (int rr = 0; rr < 4; ++rr) {
        const long row = row0 + r0 + rr;
        if (row < n) {
            *(float4*)(ya + row * D + c) =
                make_float4(acca[rr][0], acca[rr][1], acca[rr][2], acca[rr][3]);
            *(float4*)(yb + row * D + c) =
                make_float4(accb[rr][0], accb[rr][1], accb[rr][2], accb[rr][3]);
        }
    }
}

// ---------------------------------------------------------------------------
// Plain GEMM with optional relu store; in-place safe (block reads only the
// rows it writes, reads land in LDS before any write).
// ---------------------------------------------------------------------------
template <bool RELU_STORE>
__global__ __launch_bounds__(256) void gemm64(const float* __restrict__ x,
                                              const float* __restrict__ W,
                                              float* __restrict__ y, int n) {
    __shared__ float Ws[64][64];
    __shared__ float Xs[64][64];
    const int t = threadIdx.x;
    for (int i = t; i < 64 * 64; i += 256) Ws[i >> 6][i & 63] = W[i];
    const long row0 = (long)blockIdx.x * 64;
    const int nrow = min(64, n - (int)row0);
    {
        const float4* xv = (const float4*)(x + row0 * D);
        float4* xs = (float4*)&Xs[0][0];
        for (int i = t; i < nrow * 16; i += 256) xs[i] = xv[i];
    }
    __syncthreads();
    const int r0 = (t >> 4) * 4;
    const int c  = (t & 15) * 4;
    float acc[4][4] = {};
#pragma unroll
    for (int k = 0; k < 64; ++k) {
        const float4 w = *(const float4*)&Ws[k][c];
#pragma unroll
        for (int rr = 0; rr < 4; ++rr) {
            const float xv = Xs[r0 + rr][k];
            acc[rr][0] = fmaf(xv, w.x, acc[rr][0]);
            acc[rr][1] = fmaf(xv, w.y, acc[rr][1]);
            acc[rr][2] = fmaf(xv, w.z, acc[rr][2]);
            acc[rr][3] = fmaf(xv, w.w, acc[rr][3]);
        }
    }
#pragma unroll
    for (int rr = 0; rr < 4; ++rr) {
        const long row = row0 + r0 + rr;
        if (row < n) {
            float4 o = make_float4(acc[rr][0], acc[rr][1], acc[rr][2], acc[rr][3]);
            if (RELU_STORE) {
                o.x = fmaxf(o.x, 0.f); o.y = fmaxf(o.y, 0.f);
                o.z = fmaxf(o.z, 0.f); o.w = fmaxf(o.w, 0.f);
            }
            *(float4*)(y + row * D + c) = o;
        }
    }
}

// ---------------------------------------------------------------------------
// Bucket histogram: LDS per-block hist over <=1172 buckets, then atomic merge.
// ---------------------------------------------------------------------------
__global__ __launch_bounds__(256) void count_hist(const int* __restrict__ dst,
                                                  int ne, int nbkt,
                                                  int* __restrict__ gcount) {
    __shared__ int hist[NBKT11];
    for (int i = threadIdx.x; i < nbkt; i += 256) hist[i] = 0;
    __syncthreads();
    for (int e = blockIdx.x * 256 + threadIdx.x; e < ne; e += gridDim.x * 256)
        atomicAdd(&hist[dst[e] >> 7], 1);
    __syncthreads();
    for (int i = threadIdx.x; i < nbkt; i += 256) {
        const int h = hist[i];
        if (h) atomicAdd(&gcount[i], h);
    }
}

// ---------------------------------------------------------------------------
// Exclusive scan over n ints, single block (n ~ 3127).
// ---------------------------------------------------------------------------
__global__ __launch_bounds__(256) void scan_small(int* __restrict__ data, int n) {
    __shared__ int lds[256];
    __shared__ int carry_s;
    const int t = threadIdx.x;
    if (t == 0) carry_s = 0;
    __syncthreads();
    for (int base = 0; base < n; base += 256) {
        const int i = base + t;
        const int x = (i < n) ? data[i] : 0;
        lds[t] = x;
        __syncthreads();
        for (int off = 1; off < 256; off <<= 1) {
            const int y = (t >= off) ? lds[t - off] : 0;
            __syncthreads();
            lds[t] += y;
            __syncthreads();
        }
        const int incl = lds[t];
        const int carry = carry_s;
        __syncthreads();
        if (i < n) data[i] = carry + incl - x;
        if (t == 255) carry_s = carry + incl;
        __syncthreads();
    }
}

// ---------------------------------------------------------------------------
// Expand edges into bucket-grouped 8B records: (src | dstlocal<<20, coeff).
// Cursor-clustered writes -> ~3126 hot cache lines instead of random scatter.
// ---------------------------------------------------------------------------
__global__ __launch_bounds__(256) void expand_hbs(const int* __restrict__ src,
                                                  const int* __restrict__ dst,
                                                  const float* __restrict__ val,
                                                  const float* __restrict__ cci,
                                                  const float* __restrict__ a,
                                                  int* __restrict__ cursor,
                                                  int bktbase,
                                                  int2* __restrict__ rec, int ne) {
    const float a0 = a[0], a1 = a[1], a2 = a[2];
    for (int e = blockIdx.x * 256 + threadIdx.x; e < ne; e += gridDim.x * 256) {
        const int d = dst[e];
        const size_t b3 = (size_t)e * 3;
        const float coeff =
            val[e] * (cci[b3] * a0 + cci[b3 + 1] * a1 + cci[b3 + 2] * a2);
        const int pos = atomicAdd(&cursor[bktbase + (d >> 7)], 1);
        rec[pos] = make_int2(src[e] | ((d & 127) << 20), __float_as_int(coeff));
    }
}

__global__ __launch_bounds__(256) void expand_inc(const int* __restrict__ row,
                                                  const int* __restrict__ col,
                                                  const float* __restrict__ val,
                                                  int* __restrict__ cursor,
                                                  int2* __restrict__ rec, int ne) {
    for (int e = blockIdx.x * 256 + threadIdx.x; e < ne; e += gridDim.x * 256) {
        const int r = row[e], c = col[e];
        const int vb = __float_as_int(val[e]);
        const int p1 = atomicAdd(&cursor[BKT_BASE10 + (r >> 7)], 1);
        rec[p1] = make_int2(c | ((r & 127) << 20), vb);
        const int p2 = atomicAdd(&cursor[BKT_BASE01 + (c >> 7)], 1);
        rec[p2] = make_int2(r | ((c & 127) << 20), vb);
    }
}

// ---------------------------------------------------------------------------
// Bucket accumulate: one block per 128-row destination tile, acc in LDS
// (ds_add_f32, conflict-free). Records broadcast via wave-uniform LDS reads.
// Writes relu(sum) once per row; ADD variant adds onto existing buffer.
// ---------------------------------------------------------------------------
template <bool ADD>
__global__ __launch_bounds__(256) void bucket_accum(const int2* __restrict__ rec,
                                                    const int* __restrict__ bases,
                                                    int dirbase,
                                                    const float* __restrict__ m,
                                                    float* __restrict__ outbuf,
                                                    int n) {
    __shared__ float acc[BROWS * 64];   // 32 KB
    __shared__ int2 stg[4][64];         // 2 KB per-wave record staging
    const int t = threadIdx.x;
    const int lane = t & 63;
    const int wid = t >> 6;
    for (int i = t * 4; i < BROWS * 64; i += 1024)
        *(float4*)&acc[i] = make_float4(0.f, 0.f, 0.f, 0.f);
    __syncthreads();
    const int beg = bases[dirbase + blockIdx.x];
    const int end = bases[dirbase + blockIdx.x + 1];
    for (int base = beg + wid * 64; base < end; base += 256) {
        const int nn = min(64, end - base);
        if (lane < nn) stg[wid][lane] = rec[base + lane];
        for (int j = 0; j < nn; ++j) {
            const int2 r = stg[wid][j];  // wave-uniform -> LDS broadcast
            const float c = __int_as_float(r.y);
            const int s = r.x & 0xFFFFF;
            const int dl = r.x >> 20;
            atomicAdd(&acc[dl * 64 + lane], c * m[(size_t)s * D + lane]);
        }
    }
    __syncthreads();
    const long r0 = (long)blockIdx.x * BROWS;
    const int nrow = min(BROWS, n - (int)r0);
    float* o = outbuf + r0 * D;
    for (int i = t * 4; i < nrow * 64; i += 1024) {
        const float4 v = *(const float4*)&acc[i];
        float4 w;
        w.x = fmaxf(v.x, 0.f); w.y = fmaxf(v.y, 0.f);
        w.z = fmaxf(v.z, 0.f); w.w = fmaxf(v.w, 0.f);
        if (ADD) {
            const float4 e = *(const float4*)&o[i];
            w.x += e.x; w.y += e.y; w.z += e.z; w.w += e.w;
        }
        *(float4*)&o[i] = w;
    }
}

extern "C" void kernel_launch(void* const* d_in, const int* in_sizes, int n_in,
                              void* d_out, int out_size, void* d_ws, size_t ws_size,
                              hipStream_t stream) {
    const float* x0    = (const float*)d_in[0];
    const float* x1    = (const float*)d_in[1];
    const float* x2    = (const float*)d_in[2];
    const float* x3    = (const float*)d_in[3];
    const float* x4    = (const float*)d_in[4];
    const int*   adj0  = (const int*)d_in[5];   // [2][E0]: row0=src, row1=dst
    const float* adj0v = (const float*)d_in[6];
    const int*   adj1  = (const int*)d_in[7];   // [2][E1]
    const float* adj1v = (const float*)d_in[8];
    const int*   inc01 = (const int*)d_in[9];   // [2][NNZ01]: row0=n0-id, row1=n1-id
    const float* incv  = (const float*)d_in[10];
    const float* cci0  = (const float*)d_in[11];
    const float* cci1  = (const float*)d_in[12];
    const float* Whbs0 = (const float*)d_in[13];
    const float* ahbs0 = (const float*)d_in[14];
    const float* Whbs1 = (const float*)d_in[15];
    const float* ahbs1 = (const float*)d_in[16];
    const float* Wns_s = (const float*)d_in[17];
    const float* Wns_t = (const float*)d_in[18];
    const float* Wagg0 = (const float*)d_in[19];
    const float* Wagg1 = (const float*)d_in[20];

    float* out = (float*)d_out;

    const size_t S0 = (size_t)N0 * D;
    const size_t S1 = (size_t)N1 * D;

    // ---- workspace layout: ~125.7 MB ----
    float* m0   = (float*)d_ws;          // S0   (x0@Whbs0)
    float* m1   = m0 + S0;               // S1   (x1@Whbs1)
    float* msb  = m1 + S1;               // S1   (x1@Wns_s)
    float* mtb  = msb + S1;              // S0   (x0@Wns_t)
    int2*  rec  = (int2*)(mtb + S0);     // NREC 8B records
    int*   bases  = (int*)(rec + NREC);  // NBKT_TOT+1
    int*   cursor = bases + NBKT_TOT + 1;// NBKT_TOT

    float* s00 = out;                    // segment sums live in d_out
    float* s11 = out + S0;

    hipMemsetAsync(bases, 0, (NBKT_TOT + 1) * sizeof(int), stream);

    // Dense projections (x read once per dual GEMM)
    gemm64_dual<<<(N0 + 63) / 64, 256, 0, stream>>>(x0, Whbs0, Wns_t, m0, mtb, N0);
    gemm64_dual<<<(N1 + 63) / 64, 256, 0, stream>>>(x1, Whbs1, Wns_s, m1, msb, N1);

    // Bucket histograms (concatenated bucket space: 00 | 11 | 10 | 01)
    count_hist<<<128, 256, 0, stream>>>(adj0 + E0, E0, NBKT00, bases + BKT_BASE00);
    count_hist<<<192, 256, 0, stream>>>(adj1 + E1, E1, NBKT11, bases + BKT_BASE11);
    count_hist<<<64, 256, 0, stream>>>(inc01, NNZ01, NBKT00, bases + BKT_BASE10);
    count_hist<<<64, 256, 0, stream>>>(inc01 + NNZ01, NNZ01, NBKT11, bases + BKT_BASE01);

    // Offsets + cursors
    scan_small<<<1, 256, 0, stream>>>(bases, NBKT_TOT + 1);
    hipMemcpyAsync(cursor, bases, NBKT_TOT * sizeof(int),
                   hipMemcpyDeviceToDevice, stream);

    // Expand into bucket-grouped records (coeff computed inline)
    expand_hbs<<<512, 256, 0, stream>>>(adj0, adj0 + E0, adj0v, cci0, ahbs0,
                                        cursor, BKT_BASE00, rec, E0);
    expand_hbs<<<1024, 256, 0, stream>>>(adj1, adj1 + E1, adj1v, cci1, ahbs1,
                                         cursor, BKT_BASE11, rec, E1);
    expand_inc<<<256, 256, 0, stream>>>(inc01, inc01 + NNZ01, incv, cursor, rec,
                                        NNZ01);

    // LDS-tiled segment accumulation (atomic-free in global, relu fused)
    bucket_accum<false><<<NBKT00, 256, 0, stream>>>(rec, bases, BKT_BASE00, m0,
                                                    s00, N0);
    bucket_accum<false><<<NBKT11, 256, 0, stream>>>(rec, bases, BKT_BASE11, m1,
                                                    s11, N1);
    bucket_accum<true><<<NBKT00, 256, 0, stream>>>(rec, bases, BKT_BASE10, msb,
                                                   s00, N0);
    bucket_accum<true><<<NBKT11, 256, 0, stream>>>(rec, bases, BKT_BASE01, mtb,
                                                   s11, N1);

    // Aggregation GEMMs, in-place on d_out (relu on store)
    gemm64<true><<<(N0 + 63) / 64, 256, 0, stream>>>(s00, Wagg0, out, N0);
    gemm64<true><<<(N1 + 63) / 64, 256, 0, stream>>>(s11, Wagg1, out + S0, N1);

    // Pass-through outputs
    hipMemcpyAsync(out + S0 + S1, x2, (size_t)N2 * D * sizeof(float),
                   hipMemcpyDeviceToDevice, stream);
    hipMemcpyAsync(out + S0 + S1 + (size_t)N2 * D, x3, (size_t)N3 * D * sizeof(float),
                   hipMemcpyDeviceToDevice, stream);
    hipMemcpyAsync(out + S0 + S1 + (size_t)(N2 + N3) * D, x4,
                   (size_t)N4 * D * sizeof(float), hipMemcpyDeviceToDevice, stream);
}

// Round 5
// 2137.026 us; speedup vs baseline: 1.5260x; 1.5260x over previous
//
#include <hip/hip_runtime.h>

// Problem constants (from reference)
constexpr int N0 = 50000, N1 = 150000, N2 = 20000, N3 = 5000, N4 = 1000;
constexpr int E0 = 800000, E1 = 1500000, NNZ01 = 300000;
constexpr int D = 64;

// Coarse destination buckets: 64 rows each, LDS-accumulated.
constexpr int BROWS = 64;
constexpr int NBKT00 = (N0 + BROWS - 1) / BROWS;   // 782
constexpr int NBKT11 = (N1 + BROWS - 1) / BROWS;   // 2344
constexpr int BKT_BASE00 = 0;
constexpr int BKT_BASE11 = NBKT00;
constexpr int BKT_BASE10 = NBKT00 + NBKT11;
constexpr int BKT_BASE01 = 2 * NBKT00 + NBKT11;
constexpr int NBKT_TOT = 2 * NBKT00 + 2 * NBKT11;  // 6252
constexpr int NREC = E0 + E1 + 2 * NNZ01;          // 2.9M

// ---------------------------------------------------------------------------
// GEMM: y[n][64] = x[n][64] @ W[64][64]  (f32 vector ALU; no fp32 MFMA).
// 64-row tile, 256 threads, 4x4 outputs/thread. In-place safe.
// (Round-2 proven version — the dual-W variant spilled to scratch.)
// ---------------------------------------------------------------------------
template <bool RELU_STORE>
__global__ __launch_bounds__(256) void gemm64(const float* __restrict__ x,
                                              const float* __restrict__ W,
                                              float* __restrict__ y, int n) {
    __shared__ float Ws[64][64];
    __shared__ float Xs[64][64];
    const int t = threadIdx.x;
    for (int i = t; i < 64 * 64; i += 256) Ws[i >> 6][i & 63] = W[i];
    const long row0 = (long)blockIdx.x * 64;
    const int nrow = min(64, n - (int)row0);
    {
        const float4* xv = (const float4*)(x + row0 * D);
        float4* xs = (float4*)&Xs[0][0];
        for (int i = t; i < nrow * 16; i += 256) xs[i] = xv[i];
    }
    __syncthreads();
    const int r0 = (t >> 4) * 4;
    const int c  = (t & 15) * 4;
    float acc[4][4] = {};
#pragma unroll
    for (int k = 0; k < 64; ++k) {
        const float4 w = *(const float4*)&Ws[k][c];
#pragma unroll
        for (int rr = 0; rr < 4; ++rr) {
            const float xv = Xs[r0 + rr][k];
            acc[rr][0] = fmaf(xv, w.x, acc[rr][0]);
            acc[rr][1] = fmaf(xv, w.y, acc[rr][1]);
            acc[rr][2] = fmaf(xv, w.z, acc[rr][2]);
            acc[rr][3] = fmaf(xv, w.w, acc[rr][3]);
        }
    }
#pragma unroll
    for (int rr = 0; rr < 4; ++rr) {
        const long row = row0 + r0 + rr;
        if (row < n) {
            float4 o = make_float4(acc[rr][0], acc[rr][1], acc[rr][2], acc[rr][3]);
            if (RELU_STORE) {
                o.x = fmaxf(o.x, 0.f); o.y = fmaxf(o.y, 0.f);
                o.z = fmaxf(o.z, 0.f); o.w = fmaxf(o.w, 0.f);
            }
            *(float4*)(y + row * D + c) = o;
        }
    }
}

// ---------------------------------------------------------------------------
// Bucket histogram: LDS per-block hist, then atomic merge to global.
// ---------------------------------------------------------------------------
__global__ __launch_bounds__(256) void count_hist(const int* __restrict__ dst,
                                                  int ne, int nbkt,
                                                  int* __restrict__ gcount) {
    __shared__ int hist[NBKT11];
    for (int i = threadIdx.x; i < nbkt; i += 256) hist[i] = 0;
    __syncthreads();
    for (int e = blockIdx.x * 256 + threadIdx.x; e < ne; e += gridDim.x * 256)
        atomicAdd(&hist[dst[e] >> 6], 1);
    __syncthreads();
    for (int i = threadIdx.x; i < nbkt; i += 256) {
        const int h = hist[i];
        if (h) atomicAdd(&gcount[i], h);
    }
}

// ---------------------------------------------------------------------------
// Exclusive scan over n ints, single block (n ~ 6253).
// ---------------------------------------------------------------------------
__global__ __launch_bounds__(256) void scan_small(int* __restrict__ data, int n) {
    __shared__ int lds[256];
    __shared__ int carry_s;
    const int t = threadIdx.x;
    if (t == 0) carry_s = 0;
    __syncthreads();
    for (int base = 0; base < n; base += 256) {
        const int i = base + t;
        const int x = (i < n) ? data[i] : 0;
        lds[t] = x;
        __syncthreads();
        for (int off = 1; off < 256; off <<= 1) {
            const int y = (t >= off) ? lds[t - off] : 0;
            __syncthreads();
            lds[t] += y;
            __syncthreads();
        }
        const int incl = lds[t];
        const int carry = carry_s;
        __syncthreads();
        if (i < n) data[i] = carry + incl - x;
        if (t == 255) carry_s = carry + incl;
        __syncthreads();
    }
}

// ---------------------------------------------------------------------------
// Expand edges into bucket-grouped 8B records: (src | dstlocal<<20, coeff).
// ---------------------------------------------------------------------------
__global__ __launch_bounds__(256) void expand_hbs(const int* __restrict__ src,
                                                  const int* __restrict__ dst,
                                                  const float* __restrict__ val,
                                                  const float* __restrict__ cci,
                                                  const float* __restrict__ a,
                                                  int* __restrict__ cursor,
                                                  int bktbase,
                                                  int2* __restrict__ rec, int ne) {
    const float a0 = a[0], a1 = a[1], a2 = a[2];
    for (int e = blockIdx.x * 256 + threadIdx.x; e < ne; e += gridDim.x * 256) {
        const int d = dst[e];
        const size_t b3 = (size_t)e * 3;
        const float coeff =
            val[e] * (cci[b3] * a0 + cci[b3 + 1] * a1 + cci[b3 + 2] * a2);
        const int pos = atomicAdd(&cursor[bktbase + (d >> 6)], 1);
        rec[pos] = make_int2(src[e] | ((d & 63) << 20), __float_as_int(coeff));
    }
}

__global__ __launch_bounds__(256) void expand_inc(const int* __restrict__ row,
                                                  const int* __restrict__ col,
                                                  const float* __restrict__ val,
                                                  int* __restrict__ cursor,
                                                  int2* __restrict__ rec, int ne) {
    for (int e = blockIdx.x * 256 + threadIdx.x; e < ne; e += gridDim.x * 256) {
        const int r = row[e], c = col[e];
        const int vb = __float_as_int(val[e]);
        const int p1 = atomicAdd(&cursor[BKT_BASE10 + (r >> 6)], 1);
        rec[p1] = make_int2(c | ((r & 63) << 20), vb);
        const int p2 = atomicAdd(&cursor[BKT_BASE01 + (c >> 6)], 1);
        rec[p2] = make_int2(r | ((c & 63) << 20), vb);
    }
}

// ---------------------------------------------------------------------------
// Fused segment accumulate: one block per 64-row output tile. Processes
// direction A into a 16 KB LDS tile, stashes relu(accA) in registers,
// re-zeroes, processes direction B, writes relu(accB)+stash once.
// 1-deep prefetch of the next source row hides gather latency.
// ---------------------------------------------------------------------------
__global__ __launch_bounds__(256) void fused_accum(const int2* __restrict__ rec,
                                                   const int* __restrict__ bases,
                                                   int dirA, const float* __restrict__ mA,
                                                   int dirB, const float* __restrict__ mB,
                                                   float* __restrict__ outbuf, int n) {
    __shared__ float acc[BROWS * 64];   // 16 KB
    __shared__ int2 stg[4][64];         // 2 KB per-wave record staging
    const int t = threadIdx.x;
    const int lane = t & 63;
    const int wid = t >> 6;

#pragma unroll
    for (int q = 0; q < 4; ++q)
        *(float4*)&acc[t * 4 + q * 1024] = make_float4(0.f, 0.f, 0.f, 0.f);
    __syncthreads();

    // --- direction A ---
    {
        const int beg = bases[dirA + blockIdx.x];
        const int end = bases[dirA + blockIdx.x + 1];
        for (int base = beg + wid * 64; base < end; base += 256) {
            const int nn = min(64, end - base);
            if (lane < nn) stg[wid][lane] = rec[base + lane];
            float cur = 0.f;
            {
                const int2 r0 = stg[wid][0];
                cur = mA[(size_t)(r0.x & 0xFFFFF) * D + lane];
            }
            for (int j = 0; j < nn; ++j) {
                float nxt = 0.f;
                if (j + 1 < nn)
                    nxt = mA[(size_t)(stg[wid][j + 1].x & 0xFFFFF) * D + lane];
                const int2 r = stg[wid][j];
                atomicAdd(&acc[(r.x >> 20) * 64 + lane],
                          __int_as_float(r.y) * cur);
                cur = nxt;
            }
        }
    }
    __syncthreads();

    // stash relu(accA), re-zero
    float4 stash[4];
#pragma unroll
    for (int q = 0; q < 4; ++q) {
        const float4 v = *(const float4*)&acc[t * 4 + q * 1024];
        stash[q].x = fmaxf(v.x, 0.f); stash[q].y = fmaxf(v.y, 0.f);
        stash[q].z = fmaxf(v.z, 0.f); stash[q].w = fmaxf(v.w, 0.f);
        *(float4*)&acc[t * 4 + q * 1024] = make_float4(0.f, 0.f, 0.f, 0.f);
    }
    __syncthreads();

    // --- direction B ---
    {
        const int beg = bases[dirB + blockIdx.x];
        const int end = bases[dirB + blockIdx.x + 1];
        for (int base = beg + wid * 64; base < end; base += 256) {
            const int nn = min(64, end - base);
            if (lane < nn) stg[wid][lane] = rec[base + lane];
            float cur = 0.f;
            {
                const int2 r0 = stg[wid][0];
                cur = mB[(size_t)(r0.x & 0xFFFFF) * D + lane];
            }
            for (int j = 0; j < nn; ++j) {
                float nxt = 0.f;
                if (j + 1 < nn)
                    nxt = mB[(size_t)(stg[wid][j + 1].x & 0xFFFFF) * D + lane];
                const int2 r = stg[wid][j];
                atomicAdd(&acc[(r.x >> 20) * 64 + lane],
                          __int_as_float(r.y) * cur);
                cur = nxt;
            }
        }
    }
    __syncthreads();

    // write relu(accB) + stash, once per row
    const long r0 = (long)blockIdx.x * BROWS;
    const int nrow = min(BROWS, n - (int)r0);
    float* o = outbuf + r0 * D;
#pragma unroll
    for (int q = 0; q < 4; ++q) {
        const int i = t * 4 + q * 1024;
        if (i < nrow * 64) {
            const float4 v = *(const float4*)&acc[i];
            float4 w;
            w.x = fmaxf(v.x, 0.f) + stash[q].x;
            w.y = fmaxf(v.y, 0.f) + stash[q].y;
            w.z = fmaxf(v.z, 0.f) + stash[q].z;
            w.w = fmaxf(v.w, 0.f) + stash[q].w;
            *(float4*)&o[i] = w;
        }
    }
}

extern "C" void kernel_launch(void* const* d_in, const int* in_sizes, int n_in,
                              void* d_out, int out_size, void* d_ws, size_t ws_size,
                              hipStream_t stream) {
    const float* x0    = (const float*)d_in[0];
    const float* x1    = (const float*)d_in[1];
    const float* x2    = (const float*)d_in[2];
    const float* x3    = (const float*)d_in[3];
    const float* x4    = (const float*)d_in[4];
    const int*   adj0  = (const int*)d_in[5];   // [2][E0]: row0=src, row1=dst
    const float* adj0v = (const float*)d_in[6];
    const int*   adj1  = (const int*)d_in[7];   // [2][E1]
    const float* adj1v = (const float*)d_in[8];
    const int*   inc01 = (const int*)d_in[9];   // [2][NNZ01]
    const float* incv  = (const float*)d_in[10];
    const float* cci0  = (const float*)d_in[11];
    const float* cci1  = (const float*)d_in[12];
    const float* Whbs0 = (const float*)d_in[13];
    const float* ahbs0 = (const float*)d_in[14];
    const float* Whbs1 = (const float*)d_in[15];
    const float* ahbs1 = (const float*)d_in[16];
    const float* Wns_s = (const float*)d_in[17];
    const float* Wns_t = (const float*)d_in[18];
    const float* Wagg0 = (const float*)d_in[19];
    const float* Wagg1 = (const float*)d_in[20];

    float* out = (float*)d_out;

    const size_t S0 = (size_t)N0 * D;
    const size_t S1 = (size_t)N1 * D;

    // ---- workspace layout: ~125.7 MB ----
    float* m0   = (float*)d_ws;           // S0   (x0@Whbs0)
    float* m1   = m0 + S0;                // S1   (x1@Whbs1)
    float* msb  = m1 + S1;                // S1   (x1@Wns_s)
    float* mtb  = msb + S1;               // S0   (x0@Wns_t)
    int2*  rec  = (int2*)(mtb + S0);      // NREC 8B records
    int*   bases  = (int*)(rec + NREC);   // NBKT_TOT+1
    int*   cursor = bases + NBKT_TOT + 1; // NBKT_TOT

    float* s00 = out;                     // segment sums live in d_out
    float* s11 = out + S0;

    hipMemsetAsync(bases, 0, (NBKT_TOT + 1) * sizeof(int), stream);

    // Dense projections (separate launches — dual variant spilled to scratch)
    gemm64<false><<<(N0 + 63) / 64, 256, 0, stream>>>(x0, Whbs0, m0, N0);
    gemm64<false><<<(N1 + 63) / 64, 256, 0, stream>>>(x1, Whbs1, m1, N1);
    gemm64<false><<<(N1 + 63) / 64, 256, 0, stream>>>(x1, Wns_s, msb, N1);
    gemm64<false><<<(N0 + 63) / 64, 256, 0, stream>>>(x0, Wns_t, mtb, N0);

    // Bucket histograms (concatenated bucket space: 00 | 11 | 10 | 01)
    count_hist<<<128, 256, 0, stream>>>(adj0 + E0, E0, NBKT00, bases + BKT_BASE00);
    count_hist<<<192, 256, 0, stream>>>(adj1 + E1, E1, NBKT11, bases + BKT_BASE11);
    count_hist<<<64, 256, 0, stream>>>(inc01, NNZ01, NBKT00, bases + BKT_BASE10);
    count_hist<<<64, 256, 0, stream>>>(inc01 + NNZ01, NNZ01, NBKT11, bases + BKT_BASE01);

    // Offsets + cursors
    scan_small<<<1, 256, 0, stream>>>(bases, NBKT_TOT + 1);
    hipMemcpyAsync(cursor, bases, NBKT_TOT * sizeof(int),
                   hipMemcpyDeviceToDevice, stream);

    // Expand into bucket-grouped records (coeff computed inline)
    expand_hbs<<<512, 256, 0, stream>>>(adj0, adj0 + E0, adj0v, cci0, ahbs0,
                                        cursor, BKT_BASE00, rec, E0);
    expand_hbs<<<1024, 256, 0, stream>>>(adj1, adj1 + E1, adj1v, cci1, ahbs1,
                                         cursor, BKT_BASE11, rec, E1);
    expand_inc<<<256, 256, 0, stream>>>(inc01, inc01 + NNZ01, incv, cursor, rec,
                                        NNZ01);

    // Fused LDS-tiled segment accumulation: relu(sumA)+relu(sumB), one store
    fused_accum<<<NBKT00, 256, 0, stream>>>(rec, bases, BKT_BASE00, m0,
                                            BKT_BASE10, msb, s00, N0);
    fused_accum<<<NBKT11, 256, 0, stream>>>(rec, bases, BKT_BASE11, m1,
                                            BKT_BASE01, mtb, s11, N1);

    // Aggregation GEMMs, in-place on d_out (relu on store)
    gemm64<true><<<(N0 + 63) / 64, 256, 0, stream>>>(s00, Wagg0, out, N0);
    gemm64<true><<<(N1 + 63) / 64, 256, 0, stream>>>(s11, Wagg1, out + S0, N1);

    // Pass-through outputs
    hipMemcpyAsync(out + S0 + S1, x2, (size_t)N2 * D * sizeof(float),
                   hipMemcpyDeviceToDevice, stream);
    hipMemcpyAsync(out + S0 + S1 + (size_t)N2 * D, x3, (size_t)N3 * D * sizeof(float),
                   hipMemcpyDeviceToDevice, stream);
    hipMemcpyAsync(out + S0 + S1 + (size_t)(N2 + N3) * D, x4,
                   (size_t)N4 * D * sizeof(float), hipMemcpyDeviceToDevice, stream);
}